// Round 1
// baseline (1897.241 us; speedup 1.0000x reference)
//
#include <hip/hip_runtime.h>
#include <math.h>

#define ZDIM 256
#define FDIM 512
#define RSIZE 16
#define M1 128
#define KC 64
#define AST 72    // Abuf/Wbuf row stride in bf16 elems (64 + 8 pad -> 4-bank shift/row)
#define EST 264   // Emb row stride (256 + 8 pad)

typedef short bf8_t __attribute__((ext_vector_type(8)));
typedef float f4_t __attribute__((ext_vector_type(4)));

__device__ __forceinline__ unsigned short f2bf(float f) {
    union { float f; unsigned int u; } v; v.f = f;
    unsigned int r = v.u + 0x7fffu + ((v.u >> 16) & 1u);
    return (unsigned short)(r >> 16);
}
__device__ __forceinline__ float bf2f(unsigned short h) {
    union { unsigned int u; float f; } v; v.u = ((unsigned int)h) << 16;
    return v.f;
}

// dst[n*K + k] = bf16(src[k*N + n])   (B^T bf16 for MFMA B-fragments)
__global__ void k0_transpose(const float* __restrict__ src, unsigned short* __restrict__ dst,
                             int K, int N) {
    int idx = blockIdx.x * blockDim.x + threadIdx.x;
    if (idx >= K * N) return;
    int n = idx / K, k = idx - n * K;
    dst[idx] = f2bf(src[k * N + n]);
}

// ---------------- K1: fused  emb -> region attention -> regraw ----------------
__global__ __launch_bounds__(512, 1) void k1_region(
    const float* __restrict__ bags,
    const unsigned short* __restrict__ WTenc,   // [256][512] bf16
    const float* __restrict__ b_enc,
    const unsigned short* __restrict__ WTa1,    // [256][256] bf16
    const float* __restrict__ ba1,
    const float* __restrict__ wa2,
    float* __restrict__ regraw)                 // [nR][256]
{
    __shared__ __align__(16) unsigned short Abuf[M1 * AST];
    __shared__ __align__(16) unsigned short Wbuf[ZDIM * AST];
    __shared__ __align__(16) unsigned short Emb[M1 * EST];
    __shared__ float lsum[M1];
    __shared__ float att[M1];

    const int tid  = threadIdx.x;
    const int lane = tid & 63;
    const int wave = tid >> 6;      // 0..7
    const int wm   = wave & 1;      // M half (64 rows)
    const int wn   = wave >> 1;     // N quarter (64 cols)
    const int l15  = lane & 15;
    const int quad = lane >> 4;

    const long rowBase = (long)blockIdx.x * M1;

    if (tid < M1) lsum[tid] = 0.f;

    f4_t acc[4][4];
    #pragma unroll
    for (int i = 0; i < 4; i++)
        #pragma unroll
        for (int j = 0; j < 4; j++)
            acc[i][j] = f4_t{0.f, 0.f, 0.f, 0.f};

    const int ar = tid >> 2;            // A-stage row 0..127
    const int ac = (tid & 3) * 16;      // A-stage col chunk
    const int wr = tid >> 1;            // W-stage row 0..255
    const int wc = (tid & 1) * 32;      // W-stage col chunk

    // ---- Stage 1: emb = relu(bags @ W_enc + b_enc), kept bf16 in LDS ----
    for (int kc = 0; kc < FDIM; kc += KC) {
        {   // stage A tile [128][64] fp32 -> bf16
            const float4* s = (const float4*)(bags + (rowBase + ar) * FDIM + kc + ac);
            unsigned int* d = (unsigned int*)&Abuf[ar * AST + ac];
            #pragma unroll
            for (int j = 0; j < 4; j++) {
                float4 f = s[j];
                d[j * 2 + 0] = (unsigned int)f2bf(f.x) | ((unsigned int)f2bf(f.y) << 16);
                d[j * 2 + 1] = (unsigned int)f2bf(f.z) | ((unsigned int)f2bf(f.w) << 16);
            }
        }
        {   // stage W^T chunk [256][64] bf16
            const uint4* s = (const uint4*)(WTenc + wr * FDIM + kc + wc);
            uint4* d = (uint4*)&Wbuf[wr * AST + wc];
            d[0] = s[0]; d[1] = s[1]; d[2] = s[2]; d[3] = s[3];
        }
        __syncthreads();
        #pragma unroll
        for (int kk = 0; kk < KC; kk += 32) {
            bf8_t af[4], bfr[4];
            #pragma unroll
            for (int mt = 0; mt < 4; mt++)
                af[mt] = *(const bf8_t*)&Abuf[(wm * 64 + mt * 16 + l15) * AST + kk + quad * 8];
            #pragma unroll
            for (int nt = 0; nt < 4; nt++)
                bfr[nt] = *(const bf8_t*)&Wbuf[(wn * 64 + nt * 16 + l15) * AST + kk + quad * 8];
            #pragma unroll
            for (int mt = 0; mt < 4; mt++)
                #pragma unroll
                for (int nt = 0; nt < 4; nt++)
                    acc[mt][nt] = __builtin_amdgcn_mfma_f32_16x16x32_bf16(af[mt], bfr[nt], acc[mt][nt], 0, 0, 0);
        }
        __syncthreads();
    }

    // epilogue: bias + relu -> Emb (bf16)  [C/D layout: col=lane&15, row=quad*4+reg]
    #pragma unroll
    for (int nt = 0; nt < 4; nt++) {
        int col = wn * 64 + nt * 16 + l15;
        float bb = b_enc[col];
        #pragma unroll
        for (int mt = 0; mt < 4; mt++) {
            #pragma unroll
            for (int r = 0; r < 4; r++) {
                int row = wm * 64 + mt * 16 + quad * 4 + r;
                float v = acc[mt][nt][r] + bb;
                Emb[row * EST + col] = f2bf(v > 0.f ? v : 0.f);
            }
        }
    }
    __syncthreads();

    // ---- Stage 2: h = tanh(emb @ Wa1 + ba1); logit = h . wa2 (ba2 softmax-invariant) ----
    f4_t acc2[4][4];
    #pragma unroll
    for (int i = 0; i < 4; i++)
        #pragma unroll
        for (int j = 0; j < 4; j++)
            acc2[i][j] = f4_t{0.f, 0.f, 0.f, 0.f};

    for (int kc = 0; kc < ZDIM; kc += KC) {
        {
            const uint4* s = (const uint4*)(WTa1 + wr * ZDIM + kc + wc);
            uint4* d = (uint4*)&Wbuf[wr * AST + wc];
            d[0] = s[0]; d[1] = s[1]; d[2] = s[2]; d[3] = s[3];
        }
        __syncthreads();
        #pragma unroll
        for (int kk = 0; kk < KC; kk += 32) {
            bf8_t af[4], bfr[4];
            #pragma unroll
            for (int mt = 0; mt < 4; mt++)
                af[mt] = *(const bf8_t*)&Emb[(wm * 64 + mt * 16 + l15) * EST + kc + kk + quad * 8];
            #pragma unroll
            for (int nt = 0; nt < 4; nt++)
                bfr[nt] = *(const bf8_t*)&Wbuf[(wn * 64 + nt * 16 + l15) * AST + kk + quad * 8];
            #pragma unroll
            for (int mt = 0; mt < 4; mt++)
                #pragma unroll
                for (int nt = 0; nt < 4; nt++)
                    acc2[mt][nt] = __builtin_amdgcn_mfma_f32_16x16x32_bf16(af[mt], bfr[nt], acc2[mt][nt], 0, 0, 0);
        }
        __syncthreads();
    }

    // attention logits: per-row dot with wa2, 16-lane butterfly, LDS atomic across wn-waves
    #pragma unroll
    for (int mt = 0; mt < 4; mt++) {
        float pr[4] = {0.f, 0.f, 0.f, 0.f};
        #pragma unroll
        for (int nt = 0; nt < 4; nt++) {
            int col = wn * 64 + nt * 16 + l15;
            float b1 = ba1[col], w2 = wa2[col];
            #pragma unroll
            for (int r = 0; r < 4; r++)
                pr[r] += tanhf(acc2[mt][nt][r] + b1) * w2;
        }
        #pragma unroll
        for (int r = 0; r < 4; r++) {
            float v = pr[r];
            v += __shfl_xor(v, 1); v += __shfl_xor(v, 2);
            v += __shfl_xor(v, 4); v += __shfl_xor(v, 8);
            if (l15 == 0) atomicAdd(&lsum[wm * 64 + mt * 16 + quad * 4 + r], v);
        }
    }
    __syncthreads();

    // per-region softmax over 16 patches (rows grouped 16/region, 16-lane groups aligned)
    if (tid < M1) {
        float v = lsum[tid];
        float m = v;
        m = fmaxf(m, __shfl_xor(m, 1)); m = fmaxf(m, __shfl_xor(m, 2));
        m = fmaxf(m, __shfl_xor(m, 4)); m = fmaxf(m, __shfl_xor(m, 8));
        float e = expf(v - m);
        float s = e;
        s += __shfl_xor(s, 1); s += __shfl_xor(s, 2);
        s += __shfl_xor(s, 4); s += __shfl_xor(s, 8);
        att[tid] = e / s;
    }
    __syncthreads();

    // attention-weighted pooling -> regraw
    {
        int z = tid & 255;
        int half = tid >> 8;
        #pragma unroll
        for (int rg0 = 0; rg0 < 4; rg0++) {
            int rg = half * 4 + rg0;
            float s = 0.f;
            #pragma unroll
            for (int p = 0; p < 16; p++)
                s += att[rg * 16 + p] * bf2f(Emb[(rg * 16 + p) * EST + z]);
            regraw[((long)blockIdx.x * 8 + rg) * ZDIM + z] = s;
        }
    }
}

// ---------------- K2: regemb = BN1(regraw)@Wr + br ; slide logits ----------------
__global__ __launch_bounds__(512, 1) void k2_slide(
    const float* __restrict__ regraw,
    const unsigned short* __restrict__ WTr,
    const float* __restrict__ br,
    const unsigned short* __restrict__ WTs1,
    const float* __restrict__ bs1,
    const float* __restrict__ ws2,
    const float* __restrict__ g1, const float* __restrict__ b1,
    const float* __restrict__ m1, const float* __restrict__ v1,
    float* __restrict__ regemb,
    float* __restrict__ slogit)
{
    __shared__ __align__(16) unsigned short Abuf[M1 * EST];
    __shared__ __align__(16) unsigned short Wbuf[ZDIM * AST];
    __shared__ float lsum[M1];
    __shared__ float s1s[ZDIM], o1s[ZDIM];

    const int tid  = threadIdx.x;
    const int lane = tid & 63;
    const int wave = tid >> 6;
    const int wm   = wave & 1;
    const int wn   = wave >> 1;
    const int l15  = lane & 15;
    const int quad = lane >> 4;

    if (tid < ZDIM) {
        float rs = rsqrtf(v1[tid] + 1e-5f);
        float sc = g1[tid] * rs;
        s1s[tid] = sc;
        o1s[tid] = b1[tid] - m1[tid] * sc;
    }
    if (tid < M1) lsum[tid] = 0.f;
    __syncthreads();

    {   // stage A = BN1(regraw) as bf16 [128][256]
        int r = tid >> 2;
        int c0 = (tid & 3) * 64;
        const float* src = regraw + ((long)blockIdx.x * M1 + r) * ZDIM + c0;
        unsigned int* d = (unsigned int*)&Abuf[r * EST + c0];
        #pragma unroll
        for (int j = 0; j < 64; j += 4) {
            float4 f = *(const float4*)(src + j);
            float a0 = f.x * s1s[c0 + j + 0] + o1s[c0 + j + 0];
            float a1 = f.y * s1s[c0 + j + 1] + o1s[c0 + j + 1];
            float a2 = f.z * s1s[c0 + j + 2] + o1s[c0 + j + 2];
            float a3 = f.w * s1s[c0 + j + 3] + o1s[c0 + j + 3];
            d[(j >> 1) + 0] = (unsigned int)f2bf(a0) | ((unsigned int)f2bf(a1) << 16);
            d[(j >> 1) + 1] = (unsigned int)f2bf(a2) | ((unsigned int)f2bf(a3) << 16);
        }
    }
    __syncthreads();

    f4_t acc[4][4];
    #pragma unroll
    for (int i = 0; i < 4; i++)
        #pragma unroll
        for (int j = 0; j < 4; j++)
            acc[i][j] = f4_t{0.f, 0.f, 0.f, 0.f};

    const int wr = tid >> 1;
    const int wc = (tid & 1) * 32;

    for (int kc = 0; kc < ZDIM; kc += KC) {
        {
            const uint4* s = (const uint4*)(WTr + wr * ZDIM + kc + wc);
            uint4* d = (uint4*)&Wbuf[wr * AST + wc];
            d[0] = s[0]; d[1] = s[1]; d[2] = s[2]; d[3] = s[3];
        }
        __syncthreads();
        #pragma unroll
        for (int kk = 0; kk < KC; kk += 32) {
            bf8_t af[4], bfr[4];
            #pragma unroll
            for (int mt = 0; mt < 4; mt++)
                af[mt] = *(const bf8_t*)&Abuf[(wm * 64 + mt * 16 + l15) * EST + kc + kk + quad * 8];
            #pragma unroll
            for (int nt = 0; nt < 4; nt++)
                bfr[nt] = *(const bf8_t*)&Wbuf[(wn * 64 + nt * 16 + l15) * AST + kk + quad * 8];
            #pragma unroll
            for (int mt = 0; mt < 4; mt++)
                #pragma unroll
                for (int nt = 0; nt < 4; nt++)
                    acc[mt][nt] = __builtin_amdgcn_mfma_f32_16x16x32_bf16(af[mt], bfr[nt], acc[mt][nt], 0, 0, 0);
        }
        __syncthreads();
    }

    // epilogue: regemb = acc + br -> global fp32 + Abuf bf16 (A for GEMM2)
    #pragma unroll
    for (int nt = 0; nt < 4; nt++) {
        int col = wn * 64 + nt * 16 + l15;
        float bb = br[col];
        #pragma unroll
        for (int mt = 0; mt < 4; mt++) {
            #pragma unroll
            for (int r = 0; r < 4; r++) {
                int row = wm * 64 + mt * 16 + quad * 4 + r;
                float v = acc[mt][nt][r] + bb;
                regemb[((long)blockIdx.x * M1 + row) * ZDIM + col] = v;
                Abuf[row * EST + col] = f2bf(v);
            }
        }
    }
    __syncthreads();

    // GEMM2: tanh(regemb @ Ws1 + bs1) . ws2  (bs2 softmax-invariant)
    f4_t acc2[4][4];
    #pragma unroll
    for (int i = 0; i < 4; i++)
        #pragma unroll
        for (int j = 0; j < 4; j++)
            acc2[i][j] = f4_t{0.f, 0.f, 0.f, 0.f};

    for (int kc = 0; kc < ZDIM; kc += KC) {
        {
            const uint4* s = (const uint4*)(WTs1 + wr * ZDIM + kc + wc);
            uint4* d = (uint4*)&Wbuf[wr * AST + wc];
            d[0] = s[0]; d[1] = s[1]; d[2] = s[2]; d[3] = s[3];
        }
        __syncthreads();
        #pragma unroll
        for (int kk = 0; kk < KC; kk += 32) {
            bf8_t af[4], bfr[4];
            #pragma unroll
            for (int mt = 0; mt < 4; mt++)
                af[mt] = *(const bf8_t*)&Abuf[(wm * 64 + mt * 16 + l15) * EST + kc + kk + quad * 8];
            #pragma unroll
            for (int nt = 0; nt < 4; nt++)
                bfr[nt] = *(const bf8_t*)&Wbuf[(wn * 64 + nt * 16 + l15) * AST + kk + quad * 8];
            #pragma unroll
            for (int mt = 0; mt < 4; mt++)
                #pragma unroll
                for (int nt = 0; nt < 4; nt++)
                    acc2[mt][nt] = __builtin_amdgcn_mfma_f32_16x16x32_bf16(af[mt], bfr[nt], acc2[mt][nt], 0, 0, 0);
        }
        __syncthreads();
    }

    #pragma unroll
    for (int mt = 0; mt < 4; mt++) {
        float pr[4] = {0.f, 0.f, 0.f, 0.f};
        #pragma unroll
        for (int nt = 0; nt < 4; nt++) {
            int col = wn * 64 + nt * 16 + l15;
            float bb = bs1[col], w2 = ws2[col];
            #pragma unroll
            for (int r = 0; r < 4; r++)
                pr[r] += tanhf(acc2[mt][nt][r] + bb) * w2;
        }
        #pragma unroll
        for (int r = 0; r < 4; r++) {
            float v = pr[r];
            v += __shfl_xor(v, 1); v += __shfl_xor(v, 2);
            v += __shfl_xor(v, 4); v += __shfl_xor(v, 8);
            if (l15 == 0) atomicAdd(&lsum[wm * 64 + mt * 16 + quad * 4 + r], v);
        }
    }
    __syncthreads();
    if (tid < M1) slogit[(long)blockIdx.x * M1 + tid] = lsum[tid];
}

// ---------------- K3: global softmax over regions + final head ----------------
__global__ __launch_bounds__(1024) void k3a_max(const float* __restrict__ slogit, int n,
                                                float* __restrict__ gmax) {
    float m = -INFINITY;
    for (int i = threadIdx.x; i < n; i += 1024) m = fmaxf(m, slogit[i]);
    m = fmaxf(m, __shfl_xor(m, 32)); m = fmaxf(m, __shfl_xor(m, 16));
    m = fmaxf(m, __shfl_xor(m, 8));  m = fmaxf(m, __shfl_xor(m, 4));
    m = fmaxf(m, __shfl_xor(m, 2));  m = fmaxf(m, __shfl_xor(m, 1));
    __shared__ float wmax[16];
    if ((threadIdx.x & 63) == 0) wmax[threadIdx.x >> 6] = m;
    __syncthreads();
    if (threadIdx.x == 0) {
        float mm = wmax[0];
        for (int i = 1; i < 16; i++) mm = fmaxf(mm, wmax[i]);
        *gmax = mm;
    }
}

__global__ __launch_bounds__(256) void k3b_part(const float* __restrict__ slogit,
                                                const float* __restrict__ regemb,
                                                const float* __restrict__ gmax,
                                                float* __restrict__ pvec,
                                                float* __restrict__ pse, int rpb) {
    int z = threadIdx.x;
    long base = (long)blockIdx.x * rpb;
    float g = *gmax;
    float acc = 0.f, se = 0.f;
    for (int r = 0; r < rpb; r++) {
        float e = expf(slogit[base + r] - g);
        se += e;
        acc += e * regemb[(base + r) * ZDIM + z];
    }
    pvec[(long)blockIdx.x * ZDIM + z] = acc;
    if (z == 0) pse[blockIdx.x] = se;
}

__global__ __launch_bounds__(256) void k3c_final(const float* __restrict__ pvec,
                                                 const float* __restrict__ pse, int nb,
                                                 const float* __restrict__ g2, const float* __restrict__ b2,
                                                 const float* __restrict__ m2, const float* __restrict__ v2,
                                                 const float* __restrict__ Wc, const float* __restrict__ bc,
                                                 float* __restrict__ out) {
    int z = threadIdx.x;
    float v = 0.f;
    for (int b = 0; b < nb; b++) v += pvec[(long)b * ZDIM + z];
    __shared__ float ses;
    if (z == 0) {
        float s = 0.f;
        for (int b = 0; b < nb; b++) s += pse[b];
        ses = s;
    }
    __syncthreads();
    float slide = v / ses;
    float rs = rsqrtf(v2[z] + 1e-5f);
    float t = (slide - m2[z]) * rs * g2[z] + b2[z];
    float c0 = t * Wc[z * 2 + 0];
    float c1 = t * Wc[z * 2 + 1];
    c0 += __shfl_xor(c0, 32); c0 += __shfl_xor(c0, 16); c0 += __shfl_xor(c0, 8);
    c0 += __shfl_xor(c0, 4);  c0 += __shfl_xor(c0, 2);  c0 += __shfl_xor(c0, 1);
    c1 += __shfl_xor(c1, 32); c1 += __shfl_xor(c1, 16); c1 += __shfl_xor(c1, 8);
    c1 += __shfl_xor(c1, 4);  c1 += __shfl_xor(c1, 2);  c1 += __shfl_xor(c1, 1);
    __shared__ float p0[4], p1[4];
    if ((z & 63) == 0) { p0[z >> 6] = c0; p1[z >> 6] = c1; }
    __syncthreads();
    if (z == 0) out[0] = p0[0] + p0[1] + p0[2] + p0[3] + bc[0];
    if (z == 1) out[1] = p1[0] + p1[1] + p1[2] + p1[3] + bc[1];
}

extern "C" void kernel_launch(void* const* d_in, const int* in_sizes, int n_in,
                              void* d_out, int out_size, void* d_ws, size_t ws_size,
                              hipStream_t stream)
{
    const float* bags  = (const float*)d_in[0];
    const float* W_enc = (const float*)d_in[2];
    const float* b_enc = (const float*)d_in[3];
    const float* Wa1   = (const float*)d_in[4];
    const float* ba1   = (const float*)d_in[5];
    const float* wa2   = (const float*)d_in[6];
    const float* bn1g  = (const float*)d_in[8];
    const float* bn1b  = (const float*)d_in[9];
    const float* bn1m  = (const float*)d_in[10];
    const float* bn1v  = (const float*)d_in[11];
    const float* Wr    = (const float*)d_in[12];
    const float* br    = (const float*)d_in[13];
    const float* Ws1   = (const float*)d_in[14];
    const float* bs1   = (const float*)d_in[15];
    const float* ws2   = (const float*)d_in[16];
    const float* bn2g  = (const float*)d_in[18];
    const float* bn2b  = (const float*)d_in[19];
    const float* bn2m  = (const float*)d_in[20];
    const float* bn2v  = (const float*)d_in[21];
    const float* Wc    = (const float*)d_in[22];
    const float* bc    = (const float*)d_in[23];

    const int Nrows = in_sizes[0] / FDIM;   // 524288 patches
    const int nR    = Nrows / RSIZE;        // 32768 regions

    char* ws = (char*)d_ws;
    size_t off = 0;
    auto alloc = [&](size_t bytes) {
        void* p = ws + off;
        off = (off + bytes + 255) & ~(size_t)255;
        return p;
    };
    unsigned short* WTenc = (unsigned short*)alloc((size_t)FDIM * ZDIM * 2);
    unsigned short* WTa1  = (unsigned short*)alloc((size_t)ZDIM * ZDIM * 2);
    unsigned short* WTr   = (unsigned short*)alloc((size_t)ZDIM * ZDIM * 2);
    unsigned short* WTs1  = (unsigned short*)alloc((size_t)ZDIM * ZDIM * 2);
    float* regraw = (float*)alloc((size_t)nR * ZDIM * 4);
    float* regemb = (float*)alloc((size_t)nR * ZDIM * 4);
    float* slogit = (float*)alloc((size_t)nR * 4);
    float* gmax   = (float*)alloc(4);
    float* pvec   = (float*)alloc((size_t)256 * ZDIM * 4);
    float* pse    = (float*)alloc((size_t)256 * 4);

    hipLaunchKernelGGL(k0_transpose, dim3((FDIM * ZDIM + 255) / 256), dim3(256), 0, stream,
                       W_enc, WTenc, FDIM, ZDIM);
    hipLaunchKernelGGL(k0_transpose, dim3((ZDIM * ZDIM + 255) / 256), dim3(256), 0, stream,
                       Wa1, WTa1, ZDIM, ZDIM);
    hipLaunchKernelGGL(k0_transpose, dim3((ZDIM * ZDIM + 255) / 256), dim3(256), 0, stream,
                       Wr, WTr, ZDIM, ZDIM);
    hipLaunchKernelGGL(k0_transpose, dim3((ZDIM * ZDIM + 255) / 256), dim3(256), 0, stream,
                       Ws1, WTs1, ZDIM, ZDIM);

    hipLaunchKernelGGL(k1_region, dim3(Nrows / M1), dim3(512), 0, stream,
                       bags, WTenc, b_enc, WTa1, ba1, wa2, regraw);
    hipLaunchKernelGGL(k2_slide, dim3(nR / M1), dim3(512), 0, stream,
                       regraw, WTr, br, WTs1, bs1, ws2, bn1g, bn1b, bn1m, bn1v, regemb, slogit);
    hipLaunchKernelGGL(k3a_max, dim3(1), dim3(1024), 0, stream, slogit, nR, gmax);
    hipLaunchKernelGGL(k3b_part, dim3(256), dim3(256), 0, stream,
                       slogit, regemb, gmax, pvec, pse, nR / 256);
    hipLaunchKernelGGL(k3c_final, dim3(1), dim3(256), 0, stream,
                       pvec, pse, 256, bn2g, bn2b, bn2m, bn2v, Wc, bc, (float*)d_out);
}